// Round 5
// baseline (295.899 us; speedup 1.0000x reference)
//
#include <hip/hip_runtime.h>

// CombinedActorModel: B=1M, A=3 — MFMA restructure (R5).
// All three linear stages per actor run on v_mfma_f32_16x16x32_f16:
//   stage1: S[16x32pad] x W1[64pad x 32]  (cols 0..24 = m-rows, 32..56 = n-rows)
//   glue:   P = m .* n  (through per-wave LDS tile, C-layout -> A-layout)
//   stage2: P x Wlin[32pad x 32], softsign in-register
//   stage3: H x Wout[16pad x 32] -> channels 0..9 (gate = ch 9)
// f16 inputs (not bf16): 10-bit mantissa keeps absmax ~2e-3 vs 9.8e-3 thresh.
// Fragment layouts (learn_hip m89/m120): A[m=lane&15][k=quad*8+j],
// B[n=lane&15][k=quad*8+j], C/D col=lane&15, row=quad*4+reg.
// Prep kernel packs weights into per-lane frag order (one dwordx4 per frag)
// and bias-per-col buffers; MFMA C-init carries the bias.
// Per-wave LDS tile stride 68 floats: 272B rows = b128-aligned, 68%32=4 ->
// rows stagger 4 banks -> <=2 lanes/bank (free per m136).

typedef _Float16 half8 __attribute__((ext_vector_type(8)));
typedef float floatx4 __attribute__((ext_vector_type(4)));

#define NFRAG 21   // 3 actors * (4 stage1 + 2 stage2 + 1 stage3)

__global__ __launch_bounds__(256) void prep_frags(
    const float* __restrict__ Wmx, const float* __restrict__ bmx,
    const float* __restrict__ Wnx, const float* __restrict__ bnx,
    const float* __restrict__ Wmy, const float* __restrict__ bmy,
    const float* __restrict__ Wny, const float* __restrict__ bny,
    const float* __restrict__ Wmz, const float* __restrict__ bmz,
    const float* __restrict__ Wnz, const float* __restrict__ bnz,
    const float* __restrict__ Wlin, const float* __restrict__ blin,
    const float* __restrict__ Wout, const float* __restrict__ bout,
    _Float16* __restrict__ frag, float* __restrict__ bias)
{
    int i = threadIdx.x + blockIdx.x * blockDim.x;
    if (i < NFRAG * 512) {
        int f = i >> 9, rem = i & 511;
        int lane = rem >> 3, j = rem & 7;
        int a = f / 7, idx = f % 7;
        int colq = lane & 15, quad = lane >> 4;
        int k = quad * 8 + j;
        float v = 0.f;
        if (idx < 4) {                       // stage1 W1[c][k], c = idx*16+colq
            int c = idx * 16 + colq;
            if (c < 10)                  { if (k < 6)              v = Wmx[(a*10 + c)*6 + k]; }
            else if (c < 20)             { if (k >= 9  && k < 15)  v = Wmy[(a*10 + c-10)*6 + (k-9)]; }
            else if (c < 25)             { if (k >= 18 && k < 24)  v = Wmz[(a*5  + c-20)*6 + (k-18)]; }
            else if (c >= 32 && c < 42)  { if (k >= 6  && k < 9)   v = Wnx[(a*10 + c-32)*3 + (k-6)]; }
            else if (c >= 42 && c < 52)  { if (k >= 15 && k < 18)  v = Wny[(a*10 + c-42)*3 + (k-15)]; }
            else if (c >= 52 && c < 57)  { if (k >= 24 && k < 27)  v = Wnz[(a*5  + c-52)*3 + (k-24)]; }
        } else if (idx < 6) {                // stage2 Wlin
            int c = (idx - 4) * 16 + colq;
            if (c < 25 && k < 25) v = Wlin[(a*25 + c)*25 + k];
        } else {                             // stage3 Wout rows 0..9
            if (colq < 10 && k < 25) v = Wout[(a*15 + colq)*25 + k];
        }
        frag[(size_t)f * 512 + lane * 8 + j] = (_Float16)v;
    } else if (i < NFRAG * 512 + NFRAG * 16) {
        int r = i - NFRAG * 512;
        int f = r >> 4, colq = r & 15;
        int a = f / 7, idx = f % 7;
        float b = 0.f;
        if (idx < 4) {
            int c = idx * 16 + colq;
            if (c < 10)                 b = bmx[a*10 + c];
            else if (c < 20)            b = bmy[a*10 + c-10];
            else if (c < 25)            b = bmz[a*5  + c-20];
            else if (c >= 32 && c < 42) b = bnx[a*10 + c-32];
            else if (c >= 42 && c < 52) b = bny[a*10 + c-42];
            else if (c >= 52 && c < 57) b = bnz[a*5  + c-52];
        } else if (idx < 6) {
            int c = (idx - 4) * 16 + colq;
            if (c < 25) b = blin[a*25 + c];
        } else {
            if (colq < 10) b = bout[a*15 + colq];
        }
        bias[r] = b;
    }
}

__global__ __launch_bounds__(256) void actor_mfma(
    const float* __restrict__ spatial,
    const _Float16* __restrict__ frag,
    const float* __restrict__ bias,
    float* __restrict__ out)
{
    __shared__ float lds_s[1728];        // 64 elems * 27 feats (block staging)
    __shared__ float lds_w[4 * 1088];    // per-wave 16x68 fp32 tile

    const int t    = threadIdx.x;
    const int lane = t & 63, w = t >> 6;
    const int quad = lane >> 4, colq = lane & 15;
    const int k0   = quad * 8;
    const size_t b0 = (size_t)blockIdx.x * 64;

    // coalesced global -> LDS staging (432 float4)
    {
        const float4* g = (const float4*)(spatial + b0 * 27);
        float4* d = (float4*)lds_s;
        d[t] = g[t];
        int idx = t + 256;
        if (idx < 432) d[idx] = g[idx];
    }
    __syncthreads();

    // A1 fragment: A[m=colq][k=k0+j] from staged spatial (zero-pad k>=27)
    half8 A1;
    {
        const int e = w * 16 + colq;
        #pragma unroll
        for (int j = 0; j < 8; ++j) {
            int k = k0 + j;
            float v = lds_s[e * 27 + (k < 27 ? k : 26)];
            A1[j] = (_Float16)(k < 27 ? v : 0.f);
        }
    }

    float* myT = lds_w + w * 1088;                 // this wave's 16x68 tile
    const half8* fragv = (const half8*)frag;       // [f*64 + lane]

    floatx4 oacc[3];

    #pragma unroll
    for (int a = 0; a < 3; ++a) {
        // ---- stage1: 4 N-tiles, bias carried in C
        #pragma unroll
        for (int tt = 0; tt < 4; ++tt) {
            const int f = a * 7 + tt;
            half8 B = fragv[f * 64 + lane];
            float bb = bias[f * 16 + colq];
            floatx4 C = {bb, bb, bb, bb};
            C = __builtin_amdgcn_mfma_f32_16x16x32_f16(A1, B, C, 0, 0, 0);
            #pragma unroll
            for (int r = 0; r < 4; ++r)
                myT[(quad * 4 + r) * 68 + tt * 16 + colq] = C[r];
        }

        // ---- glue: P[row][k] = T[row][k] * T[row][32+k] -> A2 (f16)
        half8 A2;
        {
            const floatx4* row = (const floatx4*)(myT + colq * 68 + k0);
            floatx4 m0 = row[0];
            floatx4 m1 = row[1];
            const floatx4* rown = (const floatx4*)(myT + colq * 68 + 32 + k0);
            floatx4 n0 = rown[0];
            floatx4 n1 = rown[1];
            #pragma unroll
            for (int j = 0; j < 4; ++j) {
                A2[j]     = (_Float16)(m0[j] * n0[j]);
                A2[4 + j] = (_Float16)(m1[j] * n1[j]);
            }
        }

        // ---- stage2: 2 N-tiles + softsign
        float hsv[8];
        #pragma unroll
        for (int tt = 0; tt < 2; ++tt) {
            const int f = a * 7 + 4 + tt;
            half8 B = fragv[f * 64 + lane];
            float bb = bias[f * 16 + colq];
            floatx4 C = {bb, bb, bb, bb};
            C = __builtin_amdgcn_mfma_f32_16x16x32_f16(A2, B, C, 0, 0, 0);
            #pragma unroll
            for (int r = 0; r < 4; ++r) {
                float v = C[r];
                hsv[tt * 4 + r] = v * __builtin_amdgcn_rcpf(1.0f + fabsf(v));
            }
        }
        #pragma unroll
        for (int tt = 0; tt < 2; ++tt)
            #pragma unroll
            for (int r = 0; r < 4; ++r)
                myT[(quad * 4 + r) * 68 + tt * 16 + colq] = hsv[tt * 4 + r];

        // ---- A3 from H (cols 25..31 are exact zeros by construction)
        half8 A3;
        {
            const floatx4* row = (const floatx4*)(myT + colq * 68 + k0);
            floatx4 h0 = row[0];
            floatx4 h1 = row[1];
            #pragma unroll
            for (int j = 0; j < 4; ++j) {
                A3[j]     = (_Float16)h0[j];
                A3[4 + j] = (_Float16)h1[j];
            }
        }

        // ---- stage3: 1 tile -> channels 0..9 (10..15 junk)
        {
            const int f = a * 7 + 6;
            half8 B = fragv[f * 64 + lane];
            float bb = bias[f * 16 + colq];
            floatx4 C = {bb, bb, bb, bb};
            oacc[a] = __builtin_amdgcn_mfma_f32_16x16x32_f16(A3, B, C, 0, 0, 0);
        }
    }

    // ---- epilogue: softmax over actors of channel 9, weighted sum ch 0..8
    float res[4];
    const int src9 = (lane & 48) | 9;      // lane holding ch 9 of this row-quad
    #pragma unroll
    for (int r = 0; r < 4; ++r) {
        float g0 = __shfl(oacc[0][r], src9, 64);
        float g1 = __shfl(oacc[1][r], src9, 64);
        float g2 = __shfl(oacc[2][r], src9, 64);
        float mx = fmaxf(g0, fmaxf(g1, g2));
        float e0 = __expf(g0 - mx);
        float e1 = __expf(g1 - mx);
        float e2 = __expf(g2 - mx);
        float inv = __builtin_amdgcn_rcpf(e0 + e1 + e2);
        res[r] = (oacc[0][r] * e0 + oacc[1][r] * e1 + oacc[2][r] * e2) * inv;
    }

    // compact to LDS (same wave, no barrier), then coalesced float4 store
    if (colq < 9) {
        #pragma unroll
        for (int r = 0; r < 4; ++r)
            myT[(quad * 4 + r) * 9 + colq] = res[r];
    }
    if (lane < 36) {
        floatx4 v = *(const floatx4*)(myT + lane * 4);
        *(floatx4*)(out + (b0 + w * 16) * 9 + lane * 4) = v;
    }
}

extern "C" void kernel_launch(void* const* d_in, const int* in_sizes, int n_in,
                              void* d_out, int out_size, void* d_ws, size_t ws_size,
                              hipStream_t stream) {
    const float* spatial = (const float*)d_in[0];
    // d_in[1] = car_stats: unused by the model, never read.
    const float* Wmx  = (const float*)d_in[2];
    const float* bmx  = (const float*)d_in[3];
    const float* Wnx  = (const float*)d_in[4];
    const float* bnx  = (const float*)d_in[5];
    const float* Wmy  = (const float*)d_in[6];
    const float* bmy  = (const float*)d_in[7];
    const float* Wny  = (const float*)d_in[8];
    const float* bny  = (const float*)d_in[9];
    const float* Wmz  = (const float*)d_in[10];
    const float* bmz  = (const float*)d_in[11];
    const float* Wnz  = (const float*)d_in[12];
    const float* bnz  = (const float*)d_in[13];
    const float* Wlin = (const float*)d_in[14];
    const float* blin = (const float*)d_in[15];
    const float* Wout = (const float*)d_in[16];
    const float* bout = (const float*)d_in[17];
    float* out = (float*)d_out;

    _Float16* frag = (_Float16*)d_ws;                          // 21504 B
    float*    bias = (float*)((char*)d_ws + NFRAG * 512 * 2);  // 1344 B

    prep_frags<<<dim3(44), dim3(256), 0, stream>>>(
        Wmx, bmx, Wnx, bnx, Wmy, bmy, Wny, bny, Wmz, bmz, Wnz, bnz,
        Wlin, blin, Wout, bout, frag, bias);

    const int nb = in_sizes[0] / 27;          // 1048576, multiple of 64
    dim3 grid(nb / 64);                        // 16384 blocks, 256 thr = 4 waves
    actor_mfma<<<grid, dim3(256), 0, stream>>>(spatial, frag, bias, out);
}

// Round 6
// 258.738 us; speedup vs baseline: 1.1436x; 1.1436x over previous
//
#include <hip/hip_runtime.h>

// CombinedActorModel: B=1M, A=3 — R6: flipped-operand MFMA, zero inter-stage
// data movement.
// Every stage computes D[m=weight_row][n=element]: A-operand = weights,
// B-operand = activations. Since A and B fragment layouts are the same
// function of lane ([idx=lane&15][k=quad*8+j], m120/m89 + R5's pass), a
// stage's D output (n=e in lane&15, row=quad*4+r) is directly consumable as
// the next stage's B operand under the k-permutation
//   sigma(q,j) = 16*(j>>2) + 4*q + (j&3)
// applied to BOTH operands (dot product invariant). The prep kernel bakes
// sigma into the Wlin/Wout fragments, so stage1->glue->stage2->softsign->
// stage3 is pure in-register arithmetic: no LDS round trips, no shuffles.
// Gate broadcast: 3 __shfl in the epilogue. Frags+bias (22.8KB, shared by
// every block) staged global->LDS once per block.

typedef _Float16 half8  __attribute__((ext_vector_type(8)));
typedef float    floatx4 __attribute__((ext_vector_type(4)));

#define NFRAG 21                    // 3 actors * (4 stage1 + 2 stage2 + 1 stage3)
#define FRAG_HALFS (NFRAG * 512)    // 10752 halfs = 21504 B
#define BIAS_FLOATS (NFRAG * 16)    // 336 floats

__global__ __launch_bounds__(256) void prep_frags(
    const float* __restrict__ Wmx, const float* __restrict__ bmx,
    const float* __restrict__ Wnx, const float* __restrict__ bnx,
    const float* __restrict__ Wmy, const float* __restrict__ bmy,
    const float* __restrict__ Wny, const float* __restrict__ bny,
    const float* __restrict__ Wmz, const float* __restrict__ bmz,
    const float* __restrict__ Wnz, const float* __restrict__ bnz,
    const float* __restrict__ Wlin, const float* __restrict__ blin,
    const float* __restrict__ Wout, const float* __restrict__ bout,
    _Float16* __restrict__ frag, float* __restrict__ bias)
{
    int i = threadIdx.x + blockIdx.x * blockDim.x;
    if (i < FRAG_HALFS) {
        int f = i >> 9, rem = i & 511;
        int lane = rem >> 3, j = rem & 7;
        int q = lane >> 4, m = lane & 15;
        int a = f / 7, idx = f % 7;
        float v = 0.f;
        if (idx < 4) {
            // stage1 A-frag: rows = stage1 cols c, k = feature (standard 8q+j)
            int c = m + ((idx & 1) ? 16 : 0);
            int k = 8 * q + j;
            bool npart = (idx >= 2);
            if (c < 10) {
                if (!npart) { if (k < 6)             v = Wmx[(a*10 + c)*6 + k]; }
                else        { if (k >= 6 && k < 9)   v = Wnx[(a*10 + c)*3 + (k-6)]; }
            } else if (c < 20) {
                if (!npart) { if (k >= 9 && k < 15)  v = Wmy[(a*10 + c-10)*6 + (k-9)]; }
                else        { if (k >= 15 && k < 18) v = Wny[(a*10 + c-10)*3 + (k-15)]; }
            } else if (c < 25) {
                if (!npart) { if (k >= 18 && k < 24) v = Wmz[(a*5 + c-20)*6 + (k-18)]; }
                else        { if (k >= 24 && k < 27) v = Wnz[(a*5 + c-20)*3 + (k-24)]; }
            }
        } else if (idx < 6) {
            // stage2 A-frag: rows = o, k permuted by sigma
            int o  = m + ((idx == 5) ? 16 : 0);
            int kc = 16 * (j >> 2) + 4 * q + (j & 3);   // sigma(q,j)
            if (o < 25 && kc < 25) v = Wlin[(a*25 + o)*25 + kc];
        } else {
            // stage3 A-frag: rows = ch, k permuted by sigma
            int ko = 16 * (j >> 2) + 4 * q + (j & 3);
            if (m < 10 && ko < 25) v = Wout[(a*15 + m)*25 + ko];
        }
        frag[(size_t)f * 512 + lane * 8 + j] = (_Float16)v;
    } else if (i < FRAG_HALFS + BIAS_FLOATS) {
        int r = i - FRAG_HALFS;
        int f = r >> 4, m = r & 15;
        int a = f / 7, idx = f % 7;
        float b = 0.f;
        if (idx < 4) {
            int c = m + ((idx & 1) ? 16 : 0);
            bool npart = (idx >= 2);
            if (c < 10)      b = npart ? bnx[a*10 + c]      : bmx[a*10 + c];
            else if (c < 20) b = npart ? bny[a*10 + c-10]   : bmy[a*10 + c-10];
            else if (c < 25) b = npart ? bnz[a*5 + c-20]    : bmz[a*5 + c-20];
        } else if (idx < 6) {
            int o = m + ((idx == 5) ? 16 : 0);
            if (o < 25) b = blin[a*25 + o];
        } else {
            if (m < 10) b = bout[a*15 + m];
        }
        bias[r] = b;
    }
}

__global__ __launch_bounds__(256) void actor_mfma(
    const float* __restrict__ spatial,
    const _Float16* __restrict__ frag,
    const float* __restrict__ bias,
    float* __restrict__ out)
{
    __shared__ float    lds_s[1728];          // 64 elems * 27 feats; reused for out staging
    __shared__ _Float16 lds_f[FRAG_HALFS];    // 21504 B
    __shared__ float    lds_b[BIAS_FLOATS];   // 1344 B

    const int t = threadIdx.x;
    const int lane = t & 63, w = t >> 6;
    const int q = lane >> 4, e = lane & 15;
    const size_t b0 = (size_t)blockIdx.x * 64;

    // ---- cooperative staging: spatial(432 f4) + frags(1344 f4) + bias(84 f4)
    {
        const float4* g  = (const float4*)(spatial + b0 * 27);
        float4* d4 = (float4*)lds_s;
        d4[t] = g[t];
        if (t + 256 < 432) d4[t + 256] = g[t + 256];
        const float4* gf = (const float4*)frag;
        float4* df = (float4*)lds_f;
        #pragma unroll
        for (int k = 0; k < 6; ++k) {
            int idx = t + k * 256;
            if (idx < 1344) df[idx] = gf[idx];
        }
        const float4* gb = (const float4*)bias;
        float4* db = (float4*)lds_b;
        if (t < 84) db[t] = gb[t];
    }
    __syncthreads();

    // ---- B operand for stage1: S[e][k=8q+j], this wave's element = w*16+e
    half8 Bs;
    {
        const float* src = lds_s + (w * 16 + e) * 27 + 8 * q;
        #pragma unroll
        for (int j = 0; j < 8; ++j) {
            int k = 8 * q + j;
            Bs[j] = (_Float16)(k < 27 ? src[j] : 0.f);
        }
    }

    const half8*   fL = (const half8*)lds_f;    // fL[f*64 + lane]
    const floatx4* bL = (const floatx4*)lds_b;  // bL[f*4 + q] = bias rows 4q..4q+3

    floatx4 oacc[3];

    #pragma unroll
    for (int a = 0; a < 3; ++a) {
        const int fb = a * 7;
        // stage1: D[c][e]; tiles 0,1 = m-part, 2,3 = n-part (bias in C)
        floatx4 M0 = __builtin_amdgcn_mfma_f32_16x16x32_f16(fL[(fb+0)*64+lane], Bs, bL[(fb+0)*4+q], 0,0,0);
        floatx4 M1 = __builtin_amdgcn_mfma_f32_16x16x32_f16(fL[(fb+1)*64+lane], Bs, bL[(fb+1)*4+q], 0,0,0);
        floatx4 N0 = __builtin_amdgcn_mfma_f32_16x16x32_f16(fL[(fb+2)*64+lane], Bs, bL[(fb+2)*4+q], 0,0,0);
        floatx4 N1 = __builtin_amdgcn_mfma_f32_16x16x32_f16(fL[(fb+3)*64+lane], Bs, bL[(fb+3)*4+q], 0,0,0);

        // glue: P[e][c] = M*N, already in sigma-packed B-operand layout
        half8 P;
        #pragma unroll
        for (int r = 0; r < 4; ++r) {
            P[r]     = (_Float16)(M0[r] * N0[r]);
            P[4 + r] = (_Float16)(M1[r] * N1[r]);
        }

        // stage2: D[o][e] (Wlin frag is sigma-packed)
        floatx4 H0 = __builtin_amdgcn_mfma_f32_16x16x32_f16(fL[(fb+4)*64+lane], P, bL[(fb+4)*4+q], 0,0,0);
        floatx4 H1 = __builtin_amdgcn_mfma_f32_16x16x32_f16(fL[(fb+5)*64+lane], P, bL[(fb+5)*4+q], 0,0,0);

        // softsign -> sigma-packed B operand for stage3
        half8 Hh;
        #pragma unroll
        for (int r = 0; r < 4; ++r) {
            float v0 = H0[r];
            Hh[r]     = (_Float16)(v0 * __builtin_amdgcn_rcpf(1.0f + fabsf(v0)));
            float v1 = H1[r];
            Hh[4 + r] = (_Float16)(v1 * __builtin_amdgcn_rcpf(1.0f + fabsf(v1)));
        }

        // stage3: D[ch][e]; lane (e,q) reg r holds ch = 4q+r (gate ch9 @ q=2,r=1)
        oacc[a] = __builtin_amdgcn_mfma_f32_16x16x32_f16(fL[(fb+6)*64+lane], Hh, bL[(fb+6)*4+q], 0,0,0);
    }

    // ---- epilogue: softmax over actors of ch9, weighted sum of ch0..8
    const int src9 = 32 + e;   // lane (e, q=2); its reg1 = ch9
    float g0 = __shfl(oacc[0][1], src9, 64);
    float g1 = __shfl(oacc[1][1], src9, 64);
    float g2 = __shfl(oacc[2][1], src9, 64);
    float mx = fmaxf(g0, fmaxf(g1, g2));
    float e0 = __expf(g0 - mx);
    float e1 = __expf(g1 - mx);
    float e2 = __expf(g2 - mx);
    float inv = __builtin_amdgcn_rcpf(e0 + e1 + e2);
    e0 *= inv; e1 *= inv; e2 *= inv;

    float res[4];
    #pragma unroll
    for (int r = 0; r < 4; ++r)
        res[r] = oacc[0][r] * e0 + oacc[1][r] * e1 + oacc[2][r] * e2;

    // ---- compact to this wave's (now-free) staging slice, coalesced store
    float* ldso = lds_s + w * 432;
    if (q < 2) {
        #pragma unroll
        for (int r = 0; r < 4; ++r) ldso[e * 9 + 4 * q + r] = res[r];
    } else if (q == 2) {
        ldso[e * 9 + 8] = res[0];
    }
    // same-wave DS ordering: writes retire before the reads below issue
    if (lane < 36) {
        float4 v = *(const float4*)(ldso + lane * 4);
        *(float4*)(out + (b0 + w * 16) * 9 + lane * 4) = v;
    }
}

extern "C" void kernel_launch(void* const* d_in, const int* in_sizes, int n_in,
                              void* d_out, int out_size, void* d_ws, size_t ws_size,
                              hipStream_t stream) {
    const float* spatial = (const float*)d_in[0];
    // d_in[1] = car_stats: unused by the model, never read.
    const float* Wmx  = (const float*)d_in[2];
    const float* bmx  = (const float*)d_in[3];
    const float* Wnx  = (const float*)d_in[4];
    const float* bnx  = (const float*)d_in[5];
    const float* Wmy  = (const float*)d_in[6];
    const float* bmy  = (const float*)d_in[7];
    const float* Wny  = (const float*)d_in[8];
    const float* bny  = (const float*)d_in[9];
    const float* Wmz  = (const float*)d_in[10];
    const float* bmz  = (const float*)d_in[11];
    const float* Wnz  = (const float*)d_in[12];
    const float* bnz  = (const float*)d_in[13];
    const float* Wlin = (const float*)d_in[14];
    const float* blin = (const float*)d_in[15];
    const float* Wout = (const float*)d_in[16];
    const float* bout = (const float*)d_in[17];
    float* out = (float*)d_out;

    _Float16* frag = (_Float16*)d_ws;                            // 21504 B
    float*    bias = (float*)((char*)d_ws + FRAG_HALFS * 2);     // 1344 B

    prep_frags<<<dim3(44), dim3(256), 0, stream>>>(
        Wmx, bmx, Wnx, bnx, Wmy, bmy, Wny, bny, Wmz, bmz, Wnz, bnz,
        Wlin, blin, Wout, bout, frag, bias);

    const int nb = in_sizes[0] / 27;          // 1048576, multiple of 64
    dim3 grid(nb / 64);                        // 16384 blocks, 4 waves each
    actor_mfma<<<grid, dim3(256), 0, stream>>>(spatial, frag, bias, out);
}